// Round 15
// baseline (262.618 us; speedup 1.0000x reference)
//
#include <hip/hip_runtime.h>
#include <hip/hip_bf16.h>

// Problem sizes
#define BB 8
#define CC 192
#define C3 576
#define NH 4
#define CH 48
#define HH 128
#define WW 128
#define HW 16384
#define FF 6144

typedef short s16x8 __attribute__((ext_vector_type(8)));
typedef float f32x4 __attribute__((ext_vector_type(4)));

constexpr size_t SPM = 32ull * 128 * 128;  // elems per partial-S chunk (fp32)

// workspace layout (bytes)
constexpr size_t OFF_XT  = 0;                           // bf16 vT [32][6144][128]
constexpr size_t SZ_XT   = (size_t)BB * HW * CC * 2;
constexpr size_t OFF_WQ  = OFF_XT + SZ_XT;              // bf16 w_qkv [576][192]
constexpr size_t SZ_WQ   = (size_t)C3 * CC * 2;
constexpr size_t OFF_WP  = OFF_WQ + SZ_WQ;              // bf16 w_proj [192][192]
constexpr size_t SZ_WP   = (size_t)CC * CC * 2;
constexpr size_t OFF_RAW = OFF_WP + SZ_WP;              // bf16 qkvraw; later pvout
constexpr size_t SZ_RAW  = (size_t)BB * C3 * HW * 2;
constexpr size_t OFF_DW  = OFF_RAW + SZ_RAW;            // bf16 qkv post-dw (q,k used)
constexpr size_t OFF_SP  = OFF_DW + SZ_RAW;             // fp32 partial S; psum aliased
constexpr size_t OFF_ATB = OFF_SP + 8 * SPM * 4;        // bf16 attn [32][128][128]
constexpr size_t OFF_RQ  = OFF_ATB + 32ull * 128 * 128 * 2;
constexpr size_t OFF_RK  = OFF_RQ + 32 * 128 * 4;
constexpr size_t OFF_PS  = OFF_SP;                      // fp32 psum [8][128][384]

__device__ __forceinline__ short bf16bits(float v) {
  __hip_bfloat16 t = __float2bfloat16(v);
  return *reinterpret_cast<short*>(&t);
}
__device__ __forceinline__ float b2f(short u) {
  union { unsigned int i; float f; } x;
  x.i = ((unsigned int)(unsigned short)u) << 16;
  return x.f;
}

__device__ __forceinline__ void gload16(const void* g, void* l) {
  __builtin_amdgcn_global_load_lds((const __attribute__((address_space(1))) unsigned int*)g,
                                   (__attribute__((address_space(3))) unsigned int*)l, 16, 0, 0);
}

// counted vmcnt wait (T4)
#define VMWAIT(N) asm volatile("s_waitcnt vmcnt(" #N ")" ::: "memory")
__device__ __forceinline__ void vmdrain() { asm volatile("s_waitcnt vmcnt(0)" ::: "memory"); }
// lgkm-only barrier (publish LDS writes without draining global stores)
__device__ __forceinline__ void ldsbar() {
  asm volatile("s_waitcnt lgkmcnt(0)" ::: "memory");
  __builtin_amdgcn_s_barrier();
}

// merged weight convert
__global__ __launch_bounds__(256) void k_cvt_w2(const float* __restrict__ in1, int n1,
                                                const float* __restrict__ in2, int n2,
                                                __hip_bfloat16* __restrict__ out) {
  const int i = blockIdx.x * 256 + threadIdx.x;
  if (i < n1) out[i] = __float2bfloat16(in1[i]);
  else if (i < n1 + n2) out[i] = __float2bfloat16(in2[i - n1]);
}

// MFMA bf16 GEMM (qkv) v4: cvt_t FUSED. A (=W) resident 36KB; B built in-register
// from fp32 x (coalesced per-k rows, cvt, ds_write into the r6-validated fragment
// enumeration). T14 issue-early/write-late: loads for stage kc+1 issue before the
// MFMAs of kc; the ds_write's data dependency supplies the exact vmcnt wait.
// A-gloads are issued FIRST, so FIFO retirement via B-load waits retires A too.
__global__ __launch_bounds__(256) void k_gemm(const float* __restrict__ x,
                                              const __hip_bfloat16* __restrict__ Wb,
                                              __hip_bfloat16* __restrict__ out) {
  const int pG = blockIdx.x * 4;
  const int mBase = blockIdx.y * 96;
  const int b = blockIdx.z;
  __shared__ char smem[53248];  // A 36864 | B 2x8192 (E [48][136] unions B)
  const int tid = threadIdx.x, wave = tid >> 6, lane = tid & 63;
  const int wm = wave >> 1, wn = wave & 1;  // wave tile 48x64
  const float* xb = x + (size_t)b * CC * HW;
  char* Bbase = smem + 36864;

  // stage full A resident FIRST: [kc(6)][mf(6)][kg(4)][row(16)][8el]
#pragma unroll
  for (int it = 0; it < 9; ++it) {
    const int s = it * 256 + tid;
    const int kc = s / 384, ci = s % 384;
    const int row = ci & 15, kg = (ci >> 4) & 3, mf = ci >> 6;
    gload16(Wb + (size_t)(mBase + mf * 16 + row) * CC + kc * 32 + kg * 8,
            smem + it * 4096 + wave * 1024);
  }

  const int p0 = tid & 127;
  const int kgsel = tid >> 7;  // k-octets {kgsel, kgsel+2}

  auto loadRegs = [&](int pt, int kc, float (&r)[16]) {
    const float* src = xb + (size_t)(kc * 32) * HW + (pG + pt) * 128 + p0;
#pragma unroll
    for (int g = 0; g < 2; ++g) {
      const int kg = kgsel + g * 2;
#pragma unroll
      for (int e = 0; e < 8; ++e) r[g * 8 + e] = src[(size_t)(kg * 8 + e) * HW];
    }
  };
  auto writeRegs = [&](int buf, const float (&r)[16]) {
    char* Blc = Bbase + buf * 8192;
#pragma unroll
    for (int g = 0; g < 2; ++g) {
      const int kg = kgsel + g * 2;
      short fr[8];
#pragma unroll
      for (int e = 0; e < 8; ++e) fr[e] = bf16bits(r[g * 8 + e]);
      *(s16x8*)(Blc + ((((p0 >> 4) * 4 + kg) * 16 + (p0 & 15)) << 4)) = *(const s16x8*)fr;
    }
  };

  short* E = (short*)Bbase;  // [48][136] two-pass epilogue tile (unions B bufs)
  const int r0 = (lane >> 4) * 4, cl = lane & 15;

  float rA[16], rB[16];
  for (int pt = 0; pt < 4; ++pt) {
    loadRegs(pt, 0, rA);
    f32x4 acc[3][4] = {};
#pragma unroll
    for (int kc = 0; kc < 6; ++kc) {
      if (kc < 5) {                      // issue next stage's loads EARLY
        if (kc & 1) loadRegs(pt, kc + 1, rA);
        else        loadRegs(pt, kc + 1, rB);
      }
      if (kc & 1) writeRegs(1, rB);      // write-late: dep supplies vmcnt wait
      else        writeRegs(0, rA);
      ldsbar();                          // publish B stage (and A on first iter)
      char* Alc = smem + kc * 6144;
      char* Blc = Bbase + (kc & 1) * 8192;
      s16x8 a[3], bf[4];
#pragma unroll
      for (int i = 0; i < 3; ++i) a[i] = *(const s16x8*)(Alc + ((wm * 3 + i) << 10) + (lane << 4));
#pragma unroll
      for (int j = 0; j < 4; ++j) bf[j] = *(const s16x8*)(Blc + ((wn * 4 + j) << 10) + (lane << 4));
#pragma unroll
      for (int i = 0; i < 3; ++i)
#pragma unroll
        for (int j = 0; j < 4; ++j)
          acc[i][j] = __builtin_amdgcn_mfma_f32_16x16x32_bf16(a[i], bf[j], acc[i][j], 0, 0, 0);
      // no trailing barrier: next reuse of this buf (kc+2's write) is fenced by
      // the intervening iteration's ldsbar (lgkmcnt(0) drains these ds_reads).
    }
    ldsbar();  // all waves' kc=5 B-reads drained before E overwrites B region
    __hip_bfloat16* ob = out + (size_t)b * C3 * HW + (pG + pt) * 128;
#pragma unroll
    for (int half = 0; half < 2; ++half) {
      if (wm == half) {
#pragma unroll
        for (int i = 0; i < 3; ++i) {
          const int lr = i * 16 + r0;
#pragma unroll
          for (int j = 0; j < 4; ++j) {
            const int col = (wn * 4 + j) * 16 + cl;
#pragma unroll
            for (int r = 0; r < 4; ++r) E[(lr + r) * 136 + col] = bf16bits(acc[i][j][r]);
          }
        }
      }
      ldsbar();
#pragma unroll
      for (int it = 0; it < 3; ++it) {
        const int vi = it * 256 + tid;             // 48 rows x 16 col-octets
        const int row = vi >> 4, c8 = (vi & 15) * 8;
        const s16x8 v = *(const s16x8*)(E + row * 136 + c8);
        *(s16x8*)(ob + (size_t)(mBase + half * 48 + row) * HW + c8) = v;
      }
      ldsbar();  // E reads retired before overwrite (next half / next pt staging)
    }
  }
}

// depthwise 3x3 pad 1 (r12-proven short-block version)
__global__ __launch_bounds__(256) void k_dwconv(const __hip_bfloat16* __restrict__ in,
                                                const float* __restrict__ wdw,
                                                __hip_bfloat16* __restrict__ out,
                                                __hip_bfloat16* __restrict__ vt,
                                                float* __restrict__ psum) {
  const int h0 = blockIdx.x * 32;
  const int c = blockIdx.y;
  const int b = blockIdx.z;
  __shared__ __hip_bfloat16 IN[34][152];  // data at cols 8..135; zeros outside
  __shared__ char TR[8192];
  const int tid = threadIdx.x;
  const __hip_bfloat16* src = in + ((size_t)b * C3 + c) * HW;
  if (tid < 68) {
    const int r = tid >> 1, col = (tid & 1) ? 136 : 0;
    *(s16x8*)(&IN[r][col]) = (s16x8){};
  }
#pragma unroll
  for (int it = 0; it < 3; ++it) {
    const int vi = it * 256 + tid;
    if (vi < 544) {
      const int r = vi >> 4, w8 = vi & 15;
      const int hg = h0 - 1 + r;
      s16x8 v = {};
      if (hg >= 0 && hg < HH) v = *(const s16x8*)(src + (size_t)hg * WW + w8 * 8);
      *(s16x8*)(&IN[r][8 + w8 * 8]) = v;
    }
  }
  const float* wp = wdw + c * 9;
  float wgt[9];
#pragma unroll
  for (int q = 0; q < 9; ++q) wgt[q] = wp[q];
  __syncthreads();

  const int hl = tid >> 3, w0 = (tid & 7) * 16;
  float res[16] = {};
#pragma unroll
  for (int dh = 0; dh < 3; ++dh) {
    const __hip_bfloat16* rp = &IN[hl + dh][0];
    const s16x8 v0 = *(const s16x8*)(rp + w0);
    const s16x8 v1 = *(const s16x8*)(rp + w0 + 8);
    const s16x8 v2 = *(const s16x8*)(rp + w0 + 16);
    const s16x8 v3 = *(const s16x8*)(rp + w0 + 24);
    float rv[18];
    rv[0] = b2f(v0[7]);
#pragma unroll
    for (int e = 0; e < 8; ++e) rv[1 + e] = b2f(v1[e]);
#pragma unroll
    for (int e = 0; e < 8; ++e) rv[9 + e] = b2f(v2[e]);
    rv[17] = b2f(v3[0]);
    const float wa = wgt[dh * 3], wb = wgt[dh * 3 + 1], wc = wgt[dh * 3 + 2];
#pragma unroll
    for (int ww = 0; ww < 16; ++ww)
      res[ww] += rv[ww] * wa + rv[ww + 1] * wb + rv[ww + 2] * wc;
  }
  if (c < 2 * CC) {  // q,k: natural layout + sumsq partial
    short pk[16];
#pragma unroll
    for (int ww = 0; ww < 16; ++ww) pk[ww] = bf16bits(res[ww]);
    __hip_bfloat16* dst = out + ((size_t)b * C3 + c) * HW + (size_t)(h0 + hl) * WW + w0;
    *(s16x8*)dst = *(const s16x8*)pk;
    *(s16x8*)(dst + 8) = *(const s16x8*)(pk + 8);
    float ss = 0.f;
#pragma unroll
    for (int ww = 0; ww < 16; ++ww) ss += res[ww] * res[ww];
#pragma unroll
    for (int off = 4; off > 0; off >>= 1) ss += __shfl_down(ss, off);
    if ((tid & 7) == 0) psum[((size_t)b * HH + h0 + hl) * 384 + c] = ss;
  } else {  // v: LDS transpose -> vt[(b*4+hd)][ch*128+w][h]
    const int rel = c - 2 * CC;
    const int hd = rel / CH, ch = rel - hd * CH;
#pragma unroll
    for (int ww = 0; ww < 16; ++ww) {
      const int w = w0 + ww;
      const int blk = ((w << 2) + (hl >> 3)) ^ ((w >> 3) & 3);
      *(short*)(TR + (blk << 4) + ((hl & 7) << 1)) = bf16bits(res[ww]);
    }
    __syncthreads();
    const int w = tid >> 1, hf = tid & 1;
    short ot[16];
#pragma unroll
    for (int j = 0; j < 2; ++j) {
      const int hh = hf * 16 + j * 8;
      const int blk = ((w << 2) + (hh >> 3)) ^ ((w >> 3) & 3);
      *(s16x8*)(ot + j * 8) = *(const s16x8*)(TR + (blk << 4));
    }
    __hip_bfloat16* vd = vt + ((size_t)(b * NH + hd) * FF + (size_t)ch * WW + w) * HH + h0 + hf * 16;
    *(s16x8*)vd = *(const s16x8*)ot;
    *(s16x8*)(vd + 8) = *(const s16x8*)(ot + 8);
  }
}

// tiny: reduce 48-ch partials -> reciprocal norms
__global__ __launch_bounds__(64) void k_norms2(const float* __restrict__ psum,
                                               float* __restrict__ rq, float* __restrict__ rk) {
  const int i = blockIdx.x;
  const int hd = blockIdx.y;
  const int b = blockIdx.z & 7;
  const int which = blockIdx.z >> 3;
  const int lane = threadIdx.x;
  float s = 0.f;
  if (lane < 48) s = psum[((size_t)b * HH + i) * 384 + which * CC + hd * CH + lane];
#pragma unroll
  for (int off = 32; off > 0; off >>= 1) s += __shfl_down(s, off);
  if (lane == 0) {
    const float n = sqrtf(s);
    float* dst = which ? rk : rq;
    dst[(b * NH + hd) * HH + i] = 1.f / fmaxf(n, 1e-12f);
  }
}

// MFMA QK^T partials: i-split (64 rows/block); 3-buffer counted-vmcnt
__global__ __launch_bounds__(256) void k_qkm(const __hip_bfloat16* __restrict__ dw,
                                             float* __restrict__ sp) {
  const int ks = blockIdx.x;
  const int bh = blockIdx.y;
  const int i0 = blockIdx.z * 64;
  const int b = bh >> 2, hd = bh & 3;
  const __hip_bfloat16* qb = dw + ((size_t)b * C3 + hd * CH) * HW;
  const __hip_bfloat16* kb = dw + ((size_t)b * C3 + CC + hd * CH) * HW;
  __shared__ char smem[36864];  // 3 bufs x (A 4KB + B 8KB)
  const int tid = threadIdx.x, wave = tid >> 6, lane = tid & 63;
  const int wm = wave >> 1, wn = wave & 1;
  f32x4 acc[2][4] = {};

  auto stage = [&](int chunk, int buf) {
    const int ch = ks * 6 + (chunk >> 2);
    const int w0 = (chunk & 3) * 32;
    char* Alc = smem + buf * 12288;
    char* Blc = Alc + 4096;
    {
      const int row = tid & 15, kg = (tid >> 4) & 3;
      gload16(qb + (size_t)ch * HW + (i0 + (tid >> 6) * 16 + row) * WW + w0 + kg * 8,
              Alc + wave * 1024);
    }
#pragma unroll
    for (int is = 0; is < 2; ++is) {
      const int ci = is * 256 + tid;
      const int col = ci & 15, kg = (ci >> 4) & 3, nf = ci >> 6;
      gload16(kb + (size_t)ch * HW + (nf * 16 + col) * WW + w0 + kg * 8,
              Blc + is * 4096 + wave * 1024);
    }
  };

  stage(0, 0);
  stage(1, 1);
  for (int chunk = 0; chunk < 24; ++chunk) {
    if (chunk < 22) stage(chunk + 2, (chunk + 2) % 3);
    if (chunk < 22) VMWAIT(6);
    else if (chunk == 22) VMWAIT(3);
    else VMWAIT(0);
    __builtin_amdgcn_s_barrier();
    char* Alc = smem + (chunk % 3) * 12288;
    char* Blc = Alc + 4096;
    s16x8 a[2], bf[4];
#pragma unroll
    for (int i = 0; i < 2; ++i) a[i] = *(const s16x8*)(Alc + ((wm * 2 + i) << 10) + (lane << 4));
#pragma unroll
    for (int j = 0; j < 4; ++j) bf[j] = *(const s16x8*)(Blc + ((wn * 4 + j) << 10) + (lane << 4));
#pragma unroll
    for (int i = 0; i < 2; ++i)
#pragma unroll
      for (int j = 0; j < 4; ++j)
        acc[i][j] = __builtin_amdgcn_mfma_f32_16x16x32_bf16(a[i], bf[j], acc[i][j], 0, 0, 0);
    __builtin_amdgcn_s_barrier();
  }
  float* o = sp + (size_t)ks * SPM + (size_t)bh * HH * HH;
  const int r0 = (lane >> 4) * 4, cl = lane & 15;
#pragma unroll
  for (int i = 0; i < 2; ++i)
#pragma unroll
    for (int j = 0; j < 4; ++j) {
      const int ii = i0 + wm * 32 + i * 16 + r0;
      const int jj = wn * 64 + j * 16 + cl;
#pragma unroll
      for (int r = 0; r < 4; ++r) o[(ii + r) * HH + jj] = acc[i][j][r];
    }
}

// reduce partials, scale, softmax -> bf16 attn (one wave per row, 4 rows/block)
__global__ __launch_bounds__(256) void k_softmax(const float* __restrict__ sp,
                                                 const float* __restrict__ rq,
                                                 const float* __restrict__ rk,
                                                 const float* __restrict__ temp,
                                                 __hip_bfloat16* __restrict__ atb) {
  const int wave = threadIdx.x >> 6, lane = threadIdx.x & 63;
  const int i = blockIdx.x * 4 + wave;
  const int bh = blockIdx.y;
  const int hd = bh & 3;
  const size_t rowoff = ((size_t)bh * HH + i) * HH;
  float s0 = 0.f, s1 = 0.f;
#pragma unroll
  for (int ks = 0; ks < 8; ++ks) {
    s0 += sp[ks * SPM + rowoff + lane];
    s1 += sp[ks * SPM + rowoff + lane + 64];
  }
  const float scale = rq[bh * HH + i] * temp[hd];
  s0 *= scale * rk[bh * HH + lane];
  s1 *= scale * rk[bh * HH + lane + 64];
  float m = fmaxf(s0, s1);
#pragma unroll
  for (int off = 32; off > 0; off >>= 1) m = fmaxf(m, __shfl_xor(m, off));
  const float e0 = expf(s0 - m), e1 = expf(s1 - m);
  float ssum = e0 + e1;
#pragma unroll
  for (int off = 32; off > 0; off >>= 1) ssum += __shfl_xor(ssum, off);
  const float inv = 1.f / ssum;
  atb[rowoff + lane] = __float2bfloat16(e0 * inv);
  atb[rowoff + lane + 64] = __float2bfloat16(e1 * inv);
}

// MFMA PV v2: A resident, 2 fs-tiles streamed
__global__ __launch_bounds__(256) void k_pvm(const __hip_bfloat16* __restrict__ atb,
                                             const __hip_bfloat16* __restrict__ vt,
                                             __hip_bfloat16* __restrict__ pvout) {
  const int fs0 = blockIdx.x * 2;
  const int bh = blockIdx.y;
  const __hip_bfloat16* ab = atb + (size_t)bh * HH * HH;
  __shared__ char smem[57344];  // A 32768 | B 3x8192
  const int tid = threadIdx.x, wave = tid >> 6, lane = tid & 63;
  const int wm = wave >> 1, wn = wave & 1;

#pragma unroll
  for (int it = 0; it < 8; ++it) {
    const int s = it * 256 + tid;
    const int kc = s >> 9, ci = s & 511;
    const int row = ci & 15, kg = (ci >> 4) & 3, mf = ci >> 6;
    gload16(ab + (size_t)(mf * 16 + row) * HH + kc * 32 + kg * 8,
            smem + it * 4096 + wave * 1024);
  }
  char* Bbase = smem + 32768;

  auto stageB = [&](int st, int buf) {
    const int fs = fs0 + (st >> 2);
    const int kj0 = (st & 3) * 32;
    const __hip_bfloat16* vb = vt + ((size_t)bh * FF + fs * 128) * HH;
    char* Blc = Bbase + buf * 8192;
#pragma unroll
    for (int is = 0; is < 2; ++is) {
      const int ci = is * 256 + tid;
      const int col = ci & 15, kg = (ci >> 4) & 3, nf = ci >> 6;
      gload16(vb + (size_t)(nf * 16 + col) * HH + kj0 + kg * 8,
              Blc + is * 4096 + wave * 1024);
    }
  };

  stageB(0, 0);
  stageB(1, 1);
  const int r0 = (lane >> 4) * 4, cl = lane & 15;
  for (int fr = 0; fr < 2; ++fr) {
    f32x4 acc[4][4] = {};
#pragma unroll
    for (int kc = 0; kc < 4; ++kc) {
      const int st = fr * 4 + kc;
      if (st < 6) stageB(st + 2, (st + 2) % 3);
      if (st < 6) VMWAIT(4);
      else if (st == 6) VMWAIT(2);
      else VMWAIT(0);
      __builtin_amdgcn_s_barrier();
      char* Alc = smem + kc * 8192;
      char* Blc = Bbase + (st % 3) * 8192;
      s16x8 a[4], bf[4];
#pragma unroll
      for (int i = 0; i < 4; ++i) a[i] = *(const s16x8*)(Alc + ((wm * 4 + i) << 10) + (lane << 4));
#pragma unroll
      for (int j = 0; j < 4; ++j) bf[j] = *(const s16x8*)(Blc + ((wn * 4 + j) << 10) + (lane << 4));
#pragma unroll
      for (int i = 0; i < 4; ++i)
#pragma unroll
        for (int j = 0; j < 4; ++j)
          acc[i][j] = __builtin_amdgcn_mfma_f32_16x16x32_bf16(a[i], bf[j], acc[i][j], 0, 0, 0);
      __builtin_amdgcn_s_barrier();
    }
    __hip_bfloat16* ob = pvout + (size_t)bh * HH * FF;
    const int fs = fs0 + fr;
#pragma unroll
    for (int i = 0; i < 4; ++i)
#pragma unroll
      for (int j = 0; j < 4; ++j) {
        const int ii = wm * 64 + i * 16 + r0;
        const int f = fs * 128 + (wn * 4 + j) * 16 + cl;
#pragma unroll
        for (int r = 0; r < 4; ++r) ob[(size_t)(ii + r) * FF + f] = __float2bfloat16(acc[i][j][r]);
      }
  }
}

// fused transpose+proj; Bfrag rebuilt per-kc
__global__ __launch_bounds__(256) void k_proj(const __hip_bfloat16* __restrict__ pv,
                                              const __hip_bfloat16* __restrict__ Wp,
                                              float* __restrict__ out) {
  const int i = blockIdx.x;
  const int b = blockIdx.y;
  __shared__ __hip_bfloat16 Al[6144];
  __shared__ __hip_bfloat16 Braw[12288];
  __shared__ __hip_bfloat16 Bfrag[4096];
  char* Alc = (char*)Al;
  char* Brc = (char*)Braw;
  char* Bfc = (char*)Bfrag;
  const int tid = threadIdx.x, wave = tid >> 6, lane = tid & 63;
  const int wm = wave >> 1, wn = wave & 1;
  f32x4 acc[6][4] = {};
  for (int hf = 0; hf < 2; ++hf) {
    if (hf) __syncthreads();
#pragma unroll
    for (int it = 0; it < 6; ++it) {
      const int vi = it * 256 + tid;
      const int r = vi >> 4, w8 = vi & 15;
      const int hi = (r >= 48) ? 1 : 0;
      const int hd = hf * 2 + hi, ch = r - hi * 48;
      const s16x8 v = *(const s16x8*)(pv + ((size_t)(b * NH + hd) * HH + i) * FF + ch * 128 + w8 * 8);
      *(s16x8*)(Brc + r * 256 + ((w8 ^ (r & 15)) << 4)) = v;
    }
    __syncthreads();
    for (int kc = 0; kc < 3; ++kc) {
      const int c0 = hf * 96 + kc * 32;
#pragma unroll
      for (int is = 0; is < 3; ++is) {
        const int ci = is * 256 + tid;
        const int row = ci & 15, kg = (ci >> 4) & 3, mf = ci >> 6;
        gload16(Wp + (size_t)(mf * 16 + row) * CC + c0 + kg * 8,
                Alc + is * 4096 + wave * 1024);
      }
#pragma unroll
      for (int it = 0; it < 2; ++it) {
        const int vi = it * 256 + tid;
        const int col = vi & 15, kg = (vi >> 4) & 3, nf = vi >> 6;
        const int w = nf * 16 + col;
        short tmp[8];
#pragma unroll
        for (int e = 0; e < 8; ++e) {
          const int r = (kc * 4 + kg) * 8 + e;
          tmp[e] = *(const short*)(Brc + r * 256 + (((w >> 3) ^ (r & 15)) << 4) + (w & 7) * 2);
        }
        *(s16x8*)(Bfc + ((nf * 64 + kg * 16 + col) << 4)) = *(const s16x8*)tmp;
      }
      vmdrain();
      __syncthreads();
      s16x8 a[6], bf[4];
#pragma unroll
      for (int mi = 0; mi < 6; ++mi)
        a[mi] = *(const s16x8*)(Alc + ((wm * 6 + mi) << 10) + (lane << 4));
#pragma unroll
      for (int j = 0; j < 4; ++j)
        bf[j] = *(const s16x8*)(Bfc + (((wn * 4 + j) * 64 + lane) << 4));
#pragma unroll
      for (int mi = 0; mi < 6; ++mi)
#pragma unroll
        for (int j = 0; j < 4; ++j)
          acc[mi][j] = __builtin_amdgcn_mfma_f32_16x16x32_bf16(a[mi], bf[j], acc[mi][j], 0, 0, 0);
      __syncthreads();
    }
  }
  const int r0 = (lane >> 4) * 4, cl = lane & 15;
#pragma unroll
  for (int mi = 0; mi < 6; ++mi) {
    const int o = (wm * 6 + mi) * 16 + r0;
#pragma unroll
    for (int j = 0; j < 4; ++j) {
      const int w = (wn * 4 + j) * 16 + cl;
      float* dst = out + ((size_t)b * CC + o) * HW + i * 128 + w;
#pragma unroll
      for (int r = 0; r < 4; ++r) dst[(size_t)r * HW] = acc[mi][j][r];
    }
  }
}

extern "C" void kernel_launch(void* const* d_in, const int* in_sizes, int n_in,
                              void* d_out, int out_size, void* d_ws, size_t ws_size,
                              hipStream_t stream) {
  const float* x     = (const float*)d_in[0];
  const float* wqkv  = (const float*)d_in[1];
  const float* wdw   = (const float*)d_in[2];
  const float* wproj = (const float*)d_in[3];
  const float* temp  = (const float*)d_in[4];

  char* ws = (char*)d_ws;
  __hip_bfloat16* vt     = (__hip_bfloat16*)(ws + OFF_XT);
  __hip_bfloat16* Wq     = (__hip_bfloat16*)(ws + OFF_WQ);
  __hip_bfloat16* Wp     = (__hip_bfloat16*)(ws + OFF_WP);
  __hip_bfloat16* qkvraw = (__hip_bfloat16*)(ws + OFF_RAW);
  __hip_bfloat16* pvout  = (__hip_bfloat16*)(ws + OFF_RAW);  // qkvraw dead after dwconv
  __hip_bfloat16* qkvdw  = (__hip_bfloat16*)(ws + OFF_DW);
  float* sp    = (float*)(ws + OFF_SP);
  float* psum  = (float*)(ws + OFF_PS);                      // aliases sp; dead before k_qkm
  __hip_bfloat16* atb = (__hip_bfloat16*)(ws + OFF_ATB);
  float* rq    = (float*)(ws + OFF_RQ);
  float* rk    = (float*)(ws + OFF_RK);

  k_cvt_w2<<<dim3((C3 * CC + CC * CC + 255) / 256), 256, 0, stream>>>(wqkv, C3 * CC, wproj, CC * CC, Wq);
  k_gemm<<<dim3(HW / 512, C3 / 96, BB), 256, 0, stream>>>(x, Wq, qkvraw);
  k_dwconv<<<dim3(HH / 32, C3, BB), 256, 0, stream>>>(qkvraw, wdw, qkvdw, vt, psum);
  k_norms2<<<dim3(HH, NH, 2 * BB), 64, 0, stream>>>(psum, rq, rk);
  k_qkm<<<dim3(8, 32, 2), 256, 0, stream>>>(qkvdw, sp);
  k_softmax<<<dim3(HH / 4, 32), 256, 0, stream>>>(sp, rq, rk, temp, atb);
  k_pvm<<<dim3(24, 32), 256, 0, stream>>>(atb, vt, pvout);
  k_proj<<<dim3(HH, BB), 256, 0, stream>>>(pvout, Wp, (float*)d_out);
}

// Round 16
// 252.037 us; speedup vs baseline: 1.0420x; 1.0420x over previous
//
#include <hip/hip_runtime.h>
#include <hip/hip_bf16.h>

// Problem sizes
#define BB 8
#define CC 192
#define C3 576
#define NH 4
#define CH 48
#define HH 128
#define WW 128
#define HW 16384
#define FF 6144

typedef short s16x8 __attribute__((ext_vector_type(8)));
typedef float f32x4 __attribute__((ext_vector_type(4)));

constexpr size_t SPM = 32ull * 128 * 128;  // elems per partial-S chunk (fp32)

// workspace layout (bytes)
constexpr size_t OFF_XT  = 0;                           // bf16 xT [8][16384][192]; later vT
constexpr size_t SZ_XT   = (size_t)BB * HW * CC * 2;
constexpr size_t OFF_WQ  = OFF_XT + SZ_XT;              // bf16 w_qkv [576][192]
constexpr size_t SZ_WQ   = (size_t)C3 * CC * 2;
constexpr size_t OFF_WP  = OFF_WQ + SZ_WQ;              // bf16 w_proj [192][192]
constexpr size_t SZ_WP   = (size_t)CC * CC * 2;
constexpr size_t OFF_RAW = OFF_WP + SZ_WP;              // bf16 qkvraw; later pvout
constexpr size_t SZ_RAW  = (size_t)BB * C3 * HW * 2;
constexpr size_t OFF_DW  = OFF_RAW + SZ_RAW;            // bf16 qkv post-dw (q,k used)
constexpr size_t OFF_SP  = OFF_DW + SZ_RAW;             // fp32 partial S [4][32][128][128]; psum aliased
constexpr size_t OFF_ATB = OFF_SP + 8 * SPM * 4;        // bf16 attn [32][128][128]
constexpr size_t OFF_RQ  = OFF_ATB + 32ull * 128 * 128 * 2;
constexpr size_t OFF_RK  = OFF_RQ + 32 * 128 * 4;
constexpr size_t OFF_PS  = OFF_SP + 4 * SPM * 4;        // fp32 psum (after the 4 used S chunks)

__device__ __forceinline__ short bf16bits(float v) {
  __hip_bfloat16 t = __float2bfloat16(v);
  return *reinterpret_cast<short*>(&t);
}
__device__ __forceinline__ float b2f(short u) {
  union { unsigned int i; float f; } x;
  x.i = ((unsigned int)(unsigned short)u) << 16;
  return x.f;
}

__device__ __forceinline__ void gload16(const void* g, void* l) {
  __builtin_amdgcn_global_load_lds((const __attribute__((address_space(1))) unsigned int*)g,
                                   (__attribute__((address_space(3))) unsigned int*)l, 16, 0, 0);
}

// counted vmcnt wait (T4)
#define VMWAIT(N) asm volatile("s_waitcnt vmcnt(" #N ")" ::: "memory")
__device__ __forceinline__ void vmdrain() { asm volatile("s_waitcnt vmcnt(0)" ::: "memory"); }
// lgkm-only barrier (publish LDS writes without draining global stores)
__device__ __forceinline__ void ldsbar() {
  asm volatile("s_waitcnt lgkmcnt(0)" ::: "memory");
  __builtin_amdgcn_s_barrier();
}

// fp32 [b][C][P] -> bf16 [b][P][C] transpose+convert (tiles 32c x 64p)
__global__ __launch_bounds__(256) void k_cvt_t(const float* __restrict__ in,
                                               __hip_bfloat16* __restrict__ outT) {
  const int p0 = blockIdx.x * 64;
  const int c0 = blockIdx.y * 32;
  const int b = blockIdx.z;
  __shared__ float t[32][65];
  const float* ib = in + (size_t)b * CC * HW;
  const int tid = threadIdx.x;
  {
    const int c = tid >> 3, pl = (tid & 7) * 8;
    const float* s = ib + (size_t)(c0 + c) * HW + p0 + pl;
#pragma unroll
    for (int j = 0; j < 8; ++j) t[c][pl + j] = s[j];
  }
  __syncthreads();
  {
    const int pl = tid >> 2, cl = (tid & 3) * 8;
    __hip_bfloat16* d = outT + (size_t)b * HW * CC + (size_t)(p0 + pl) * CC + c0 + cl;
#pragma unroll
    for (int j = 0; j < 8; ++j) d[j] = __float2bfloat16(t[cl + j][pl]);
  }
}

// merged weight convert
__global__ __launch_bounds__(256) void k_cvt_w2(const float* __restrict__ in1, int n1,
                                                const float* __restrict__ in2, int n2,
                                                __hip_bfloat16* __restrict__ out) {
  const int i = blockIdx.x * 256 + threadIdx.x;
  if (i < n1) out[i] = __float2bfloat16(in1[i]);
  else if (i < n1 + n2) out[i] = __float2bfloat16(in2[i - n1]);
}

// MFMA bf16 GEMM (qkv) v3 (r14-proven): A resident (36KB) + 2-buffer B pipeline
// + two-pass epilogue -> LDS 53,248 B -> 3 blocks/CU.
__global__ __launch_bounds__(256) void k_gemm(const __hip_bfloat16* __restrict__ xT,
                                              const __hip_bfloat16* __restrict__ Wb,
                                              __hip_bfloat16* __restrict__ out) {
  const int pG = blockIdx.x * 4;
  const int mBase = blockIdx.y * 96;
  const int b = blockIdx.z;
  __shared__ char smem[53248];             // A 36864 | B 2x8192 (E [48][136] unions B)
  const int tid = threadIdx.x, wave = tid >> 6, lane = tid & 63;
  const int wm = wave >> 1, wn = wave & 1;  // wave tile 48x64
  const __hip_bfloat16* xb = xT + (size_t)b * HW * CC;
  char* Bbase = smem + 36864;

  // stage full A resident: [kc(6)][mf(6)][kg(4)][row(16)][8el]
#pragma unroll
  for (int it = 0; it < 9; ++it) {
    const int s = it * 256 + tid;
    const int kc = s / 384, ci = s % 384;
    const int row = ci & 15, kg = (ci >> 4) & 3, mf = ci >> 6;
    gload16(Wb + (size_t)(mBase + mf * 16 + row) * CC + kc * 32 + kg * 8,
            smem + it * 4096 + wave * 1024);
  }

  auto stageB = [&](int pt, int kc, int buf) {
    char* Blc = Bbase + buf * 8192;
    const int pBase = (pG + pt) * 128;
#pragma unroll
    for (int is = 0; is < 2; ++is) {
      const int ci = is * 256 + tid;
      const int col = ci & 15, kg = (ci >> 4) & 3, nf = ci >> 6;
      gload16(xb + (size_t)(pBase + nf * 16 + col) * CC + kc * 32 + kg * 8,
              Blc + is * 4096 + wave * 1024);
    }
  };

  short* E = (short*)Bbase;  // [48][136] two-pass epilogue tile (unions B bufs)
  const int r0 = (lane >> 4) * 4, cl = lane & 15;

  for (int pt = 0; pt < 4; ++pt) {
    stageB(pt, 0, 0);
    f32x4 acc[3][4] = {};
#pragma unroll
    for (int kc = 0; kc < 6; ++kc) {
      if (kc < 5) stageB(pt, kc + 1, (kc + 1) & 1);
      // 2 loads/stage: wait(2) retires stage kc (and at kc==0 the A loads too)
      if (kc < 5) VMWAIT(2);
      else VMWAIT(0);
      __builtin_amdgcn_s_barrier();
      char* Alc = smem + kc * 6144;
      char* Blc = Bbase + (kc & 1) * 8192;
      s16x8 a[3], bf[4];
#pragma unroll
      for (int i = 0; i < 3; ++i) a[i] = *(const s16x8*)(Alc + ((wm * 3 + i) << 10) + (lane << 4));
#pragma unroll
      for (int j = 0; j < 4; ++j) bf[j] = *(const s16x8*)(Blc + ((wn * 4 + j) << 10) + (lane << 4));
#pragma unroll
      for (int i = 0; i < 3; ++i)
#pragma unroll
        for (int j = 0; j < 4; ++j)
          acc[i][j] = __builtin_amdgcn_mfma_f32_16x16x32_bf16(a[i], bf[j], acc[i][j], 0, 0, 0);
      __builtin_amdgcn_s_barrier();  // reads of buf kc&1 done before re-stage
    }
    // two-pass epilogue: 48 rows at a time; wm==half waves own the rows
    __hip_bfloat16* ob = out + (size_t)b * C3 * HW + (pG + pt) * 128;
#pragma unroll
    for (int half = 0; half < 2; ++half) {
      if (wm == half) {
#pragma unroll
        for (int i = 0; i < 3; ++i) {
          const int lr = i * 16 + r0;
#pragma unroll
          for (int j = 0; j < 4; ++j) {
            const int col = (wn * 4 + j) * 16 + cl;
#pragma unroll
            for (int r = 0; r < 4; ++r) E[(lr + r) * 136 + col] = bf16bits(acc[i][j][r]);
          }
        }
      }
      ldsbar();
#pragma unroll
      for (int it = 0; it < 3; ++it) {
        const int vi = it * 256 + tid;             // 48 rows x 16 col-octets
        const int row = vi >> 4, c8 = (vi & 15) * 8;
        const s16x8 v = *(const s16x8*)(E + row * 136 + c8);
        *(s16x8*)(ob + (size_t)(mBase + half * 48 + row) * HW + c8) = v;
      }
      ldsbar();  // E reads retired before overwrite (next half / next pt staging)
    }
  }
}

// depthwise 3x3 pad 1 (r12-proven short-block version)
__global__ __launch_bounds__(256) void k_dwconv(const __hip_bfloat16* __restrict__ in,
                                                const float* __restrict__ wdw,
                                                __hip_bfloat16* __restrict__ out,
                                                __hip_bfloat16* __restrict__ vt,
                                                float* __restrict__ psum) {
  const int h0 = blockIdx.x * 32;
  const int c = blockIdx.y;
  const int b = blockIdx.z;
  __shared__ __hip_bfloat16 IN[34][152];  // data at cols 8..135; zeros outside
  __shared__ char TR[8192];
  const int tid = threadIdx.x;
  const __hip_bfloat16* src = in + ((size_t)b * C3 + c) * HW;
  if (tid < 68) {
    const int r = tid >> 1, col = (tid & 1) ? 136 : 0;
    *(s16x8*)(&IN[r][col]) = (s16x8){};
  }
#pragma unroll
  for (int it = 0; it < 3; ++it) {
    const int vi = it * 256 + tid;
    if (vi < 544) {
      const int r = vi >> 4, w8 = vi & 15;
      const int hg = h0 - 1 + r;
      s16x8 v = {};
      if (hg >= 0 && hg < HH) v = *(const s16x8*)(src + (size_t)hg * WW + w8 * 8);
      *(s16x8*)(&IN[r][8 + w8 * 8]) = v;
    }
  }
  const float* wp = wdw + c * 9;
  float wgt[9];
#pragma unroll
  for (int q = 0; q < 9; ++q) wgt[q] = wp[q];
  __syncthreads();

  const int hl = tid >> 3, w0 = (tid & 7) * 16;
  float res[16] = {};
#pragma unroll
  for (int dh = 0; dh < 3; ++dh) {
    const __hip_bfloat16* rp = &IN[hl + dh][0];
    const s16x8 v0 = *(const s16x8*)(rp + w0);
    const s16x8 v1 = *(const s16x8*)(rp + w0 + 8);
    const s16x8 v2 = *(const s16x8*)(rp + w0 + 16);
    const s16x8 v3 = *(const s16x8*)(rp + w0 + 24);
    float rv[18];
    rv[0] = b2f(v0[7]);
#pragma unroll
    for (int e = 0; e < 8; ++e) rv[1 + e] = b2f(v1[e]);
#pragma unroll
    for (int e = 0; e < 8; ++e) rv[9 + e] = b2f(v2[e]);
    rv[17] = b2f(v3[0]);
    const float wa = wgt[dh * 3], wb = wgt[dh * 3 + 1], wc = wgt[dh * 3 + 2];
#pragma unroll
    for (int ww = 0; ww < 16; ++ww)
      res[ww] += rv[ww] * wa + rv[ww + 1] * wb + rv[ww + 2] * wc;
  }
  if (c < 2 * CC) {  // q,k: natural layout + sumsq partial
    short pk[16];
#pragma unroll
    for (int ww = 0; ww < 16; ++ww) pk[ww] = bf16bits(res[ww]);
    __hip_bfloat16* dst = out + ((size_t)b * C3 + c) * HW + (size_t)(h0 + hl) * WW + w0;
    *(s16x8*)dst = *(const s16x8*)pk;
    *(s16x8*)(dst + 8) = *(const s16x8*)(pk + 8);
    float ss = 0.f;
#pragma unroll
    for (int ww = 0; ww < 16; ++ww) ss += res[ww] * res[ww];
#pragma unroll
    for (int off = 4; off > 0; off >>= 1) ss += __shfl_down(ss, off);
    if ((tid & 7) == 0) psum[((size_t)b * HH + h0 + hl) * 384 + c] = ss;
  } else {  // v: LDS transpose -> vt[(b*4+hd)][ch*128+w][h]
    const int rel = c - 2 * CC;
    const int hd = rel / CH, ch = rel - hd * CH;
#pragma unroll
    for (int ww = 0; ww < 16; ++ww) {
      const int w = w0 + ww;
      const int blk = ((w << 2) + (hl >> 3)) ^ ((w >> 3) & 3);
      *(short*)(TR + (blk << 4) + ((hl & 7) << 1)) = bf16bits(res[ww]);
    }
    __syncthreads();
    const int w = tid >> 1, hf = tid & 1;
    short ot[16];
#pragma unroll
    for (int j = 0; j < 2; ++j) {
      const int hh = hf * 16 + j * 8;
      const int blk = ((w << 2) + (hh >> 3)) ^ ((w >> 3) & 3);
      *(s16x8*)(ot + j * 8) = *(const s16x8*)(TR + (blk << 4));
    }
    __hip_bfloat16* vd = vt + ((size_t)(b * NH + hd) * FF + (size_t)ch * WW + w) * HH + h0 + hf * 16;
    *(s16x8*)vd = *(const s16x8*)ot;
    *(s16x8*)(vd + 8) = *(const s16x8*)(ot + 8);
  }
}

// tiny: reduce 48-ch partials -> reciprocal norms
__global__ __launch_bounds__(64) void k_norms2(const float* __restrict__ psum,
                                               float* __restrict__ rq, float* __restrict__ rk) {
  const int i = blockIdx.x;
  const int hd = blockIdx.y;
  const int b = blockIdx.z & 7;
  const int which = blockIdx.z >> 3;
  const int lane = threadIdx.x;
  float s = 0.f;
  if (lane < 48) s = psum[((size_t)b * HH + i) * 384 + which * CC + hd * CH + lane];
#pragma unroll
  for (int off = 32; off > 0; off >>= 1) s += __shfl_down(s, off);
  if (lane == 0) {
    const float n = sqrtf(s);
    float* dst = which ? rk : rq;
    dst[(b * NH + hd) * HH + i] = 1.f / fmaxf(n, 1e-12f);
  }
}

// MFMA QK^T partials: K-split 4 x 1536 (halves partial-S traffic vs 8-way),
// i-split (64 rows/block); 3-buffer counted-vmcnt pipeline, 48 chunks.
__global__ __launch_bounds__(256) void k_qkm(const __hip_bfloat16* __restrict__ dw,
                                             float* __restrict__ sp) {
  const int ks = blockIdx.x;          // 0..3 (12 channels each)
  const int bh = blockIdx.y;
  const int i0 = blockIdx.z * 64;
  const int b = bh >> 2, hd = bh & 3;
  const __hip_bfloat16* qb = dw + ((size_t)b * C3 + hd * CH) * HW;
  const __hip_bfloat16* kb = dw + ((size_t)b * C3 + CC + hd * CH) * HW;
  __shared__ char smem[36864];  // 3 bufs x (A 4KB + B 8KB)
  const int tid = threadIdx.x, wave = tid >> 6, lane = tid & 63;
  const int wm = wave >> 1, wn = wave & 1;
  f32x4 acc[2][4] = {};

  auto stage = [&](int chunk, int buf) {
    const int ch = ks * 12 + (chunk >> 2);
    const int w0 = (chunk & 3) * 32;
    char* Alc = smem + buf * 12288;
    char* Blc = Alc + 4096;
    {
      const int row = tid & 15, kg = (tid >> 4) & 3;
      gload16(qb + (size_t)ch * HW + (i0 + (tid >> 6) * 16 + row) * WW + w0 + kg * 8,
              Alc + wave * 1024);
    }
#pragma unroll
    for (int is = 0; is < 2; ++is) {
      const int ci = is * 256 + tid;
      const int col = ci & 15, kg = (ci >> 4) & 3, nf = ci >> 6;
      gload16(kb + (size_t)ch * HW + (nf * 16 + col) * WW + w0 + kg * 8,
              Blc + is * 4096 + wave * 1024);
    }
  };

  stage(0, 0);
  stage(1, 1);
  for (int chunk = 0; chunk < 48; ++chunk) {
    if (chunk < 46) stage(chunk + 2, (chunk + 2) % 3);
    if (chunk < 46) VMWAIT(6);
    else if (chunk == 46) VMWAIT(3);
    else VMWAIT(0);
    __builtin_amdgcn_s_barrier();
    char* Alc = smem + (chunk % 3) * 12288;
    char* Blc = Alc + 4096;
    s16x8 a[2], bf[4];
#pragma unroll
    for (int i = 0; i < 2; ++i) a[i] = *(const s16x8*)(Alc + ((wm * 2 + i) << 10) + (lane << 4));
#pragma unroll
    for (int j = 0; j < 4; ++j) bf[j] = *(const s16x8*)(Blc + ((wn * 4 + j) << 10) + (lane << 4));
#pragma unroll
    for (int i = 0; i < 2; ++i)
#pragma unroll
      for (int j = 0; j < 4; ++j)
        acc[i][j] = __builtin_amdgcn_mfma_f32_16x16x32_bf16(a[i], bf[j], acc[i][j], 0, 0, 0);
    __builtin_amdgcn_s_barrier();
  }
  float* o = sp + (size_t)ks * SPM + (size_t)bh * HH * HH;
  const int r0 = (lane >> 4) * 4, cl = lane & 15;
#pragma unroll
  for (int i = 0; i < 2; ++i)
#pragma unroll
    for (int j = 0; j < 4; ++j) {
      const int ii = i0 + wm * 32 + i * 16 + r0;
      const int jj = wn * 64 + j * 16 + cl;
#pragma unroll
      for (int r = 0; r < 4; ++r) o[(ii + r) * HH + jj] = acc[i][j][r];
    }
}

// reduce partials (4), scale, softmax -> bf16 attn (one wave per row, 4 rows/block)
__global__ __launch_bounds__(256) void k_softmax(const float* __restrict__ sp,
                                                 const float* __restrict__ rq,
                                                 const float* __restrict__ rk,
                                                 const float* __restrict__ temp,
                                                 __hip_bfloat16* __restrict__ atb) {
  const int wave = threadIdx.x >> 6, lane = threadIdx.x & 63;
  const int i = blockIdx.x * 4 + wave;
  const int bh = blockIdx.y;
  const int hd = bh & 3;
  const size_t rowoff = ((size_t)bh * HH + i) * HH;
  float s0 = 0.f, s1 = 0.f;
#pragma unroll
  for (int ks = 0; ks < 4; ++ks) {
    s0 += sp[ks * SPM + rowoff + lane];
    s1 += sp[ks * SPM + rowoff + lane + 64];
  }
  const float scale = rq[bh * HH + i] * temp[hd];
  s0 *= scale * rk[bh * HH + lane];
  s1 *= scale * rk[bh * HH + lane + 64];
  float m = fmaxf(s0, s1);
#pragma unroll
  for (int off = 32; off > 0; off >>= 1) m = fmaxf(m, __shfl_xor(m, off));
  const float e0 = expf(s0 - m), e1 = expf(s1 - m);
  float ssum = e0 + e1;
#pragma unroll
  for (int off = 32; off > 0; off >>= 1) ssum += __shfl_xor(ssum, off);
  const float inv = 1.f / ssum;
  atb[rowoff + lane] = __float2bfloat16(e0 * inv);
  atb[rowoff + lane + 64] = __float2bfloat16(e1 * inv);
}

// MFMA PV v2: A resident, 2 fs-tiles streamed (r12-proven)
__global__ __launch_bounds__(256) void k_pvm(const __hip_bfloat16* __restrict__ atb,
                                             const __hip_bfloat16* __restrict__ vt,
                                             __hip_bfloat16* __restrict__ pvout) {
  const int fs0 = blockIdx.x * 2;
  const int bh = blockIdx.y;
  const __hip_bfloat16* ab = atb + (size_t)bh * HH * HH;
  __shared__ char smem[57344];  // A 32768 | B 3x8192
  const int tid = threadIdx.x, wave = tid >> 6, lane = tid & 63;
  const int wm = wave >> 1, wn = wave & 1;

#pragma unroll
  for (int it = 0; it < 8; ++it) {
    const int s = it * 256 + tid;
    const int kc = s >> 9, ci = s & 511;
    const int row = ci & 15, kg = (ci >> 4) & 3, mf = ci >> 6;
    gload16(ab + (size_t)(mf * 16 + row) * HH + kc * 32 + kg * 8,
            smem + it * 4096 + wave * 1024);
  }
  char* Bbase = smem + 32768;

  auto stageB = [&](int st, int buf) {
    const int fs = fs0 + (st >> 2);
    const int kj0 = (st & 3) * 32;
    const __hip_bfloat16* vb = vt + ((size_t)bh * FF + fs * 128) * HH;
    char* Blc = Bbase + buf * 8192;
#pragma unroll
    for (int is = 0; is < 2; ++is) {
      const int ci = is * 256 + tid;
      const int col = ci & 15, kg = (ci >> 4) & 3, nf = ci >> 6;
      gload16(vb + (size_t)(nf * 16 + col) * HH + kj0 + kg * 8,
              Blc + is * 4096 + wave * 1024);
    }
  };

  stageB(0, 0);
  stageB(1, 1);
  const int r0 = (lane >> 4) * 4, cl = lane & 15;
  for (int fr = 0; fr < 2; ++fr) {
    f32x4 acc[4][4] = {};
#pragma unroll
    for (int kc = 0; kc < 4; ++kc) {
      const int st = fr * 4 + kc;
      if (st < 6) stageB(st + 2, (st + 2) % 3);
      if (st < 6) VMWAIT(4);
      else if (st == 6) VMWAIT(2);
      else VMWAIT(0);
      __builtin_amdgcn_s_barrier();
      char* Alc = smem + kc * 8192;
      char* Blc = Bbase + (st % 3) * 8192;
      s16x8 a[4], bf[4];
#pragma unroll
      for (int i = 0; i < 4; ++i) a[i] = *(const s16x8*)(Alc + ((wm * 4 + i) << 10) + (lane << 4));
#pragma unroll
      for (int j = 0; j < 4; ++j) bf[j] = *(const s16x8*)(Blc + ((wn * 4 + j) << 10) + (lane << 4));
#pragma unroll
      for (int i = 0; i < 4; ++i)
#pragma unroll
        for (int j = 0; j < 4; ++j)
          acc[i][j] = __builtin_amdgcn_mfma_f32_16x16x32_bf16(a[i], bf[j], acc[i][j], 0, 0, 0);
      __builtin_amdgcn_s_barrier();
    }
    __hip_bfloat16* ob = pvout + (size_t)bh * HH * FF;
    const int fs = fs0 + fr;
#pragma unroll
    for (int i = 0; i < 4; ++i)
#pragma unroll
      for (int j = 0; j < 4; ++j) {
        const int ii = wm * 64 + i * 16 + r0;
        const int f = fs * 128 + (wn * 4 + j) * 16 + cl;
#pragma unroll
        for (int r = 0; r < 4; ++r) ob[(size_t)(ii + r) * FF + f] = __float2bfloat16(acc[i][j][r]);
      }
  }
}

// fused transpose+proj; Bfrag rebuilt per-kc (r12-proven)
__global__ __launch_bounds__(256) void k_proj(const __hip_bfloat16* __restrict__ pv,
                                              const __hip_bfloat16* __restrict__ Wp,
                                              float* __restrict__ out) {
  const int i = blockIdx.x;
  const int b = blockIdx.y;
  __shared__ __hip_bfloat16 Al[6144];
  __shared__ __hip_bfloat16 Braw[12288];
  __shared__ __hip_bfloat16 Bfrag[4096];
  char* Alc = (char*)Al;
  char* Brc = (char*)Braw;
  char* Bfc = (char*)Bfrag;
  const int tid = threadIdx.x, wave = tid >> 6, lane = tid & 63;
  const int wm = wave >> 1, wn = wave & 1;
  f32x4 acc[6][4] = {};
  for (int hf = 0; hf < 2; ++hf) {
    if (hf) __syncthreads();
#pragma unroll
    for (int it = 0; it < 6; ++it) {
      const int vi = it * 256 + tid;
      const int r = vi >> 4, w8 = vi & 15;
      const int hi = (r >= 48) ? 1 : 0;
      const int hd = hf * 2 + hi, ch = r - hi * 48;
      const s16x8 v = *(const s16x8*)(pv + ((size_t)(b * NH + hd) * HH + i) * FF + ch * 128 + w8 * 8);
      *(s16x8*)(Brc + r * 256 + ((w8 ^ (r & 15)) << 4)) = v;
    }
    __syncthreads();
    for (int kc = 0; kc < 3; ++kc) {
      const int c0 = hf * 96 + kc * 32;
#pragma unroll
      for (int is = 0; is < 3; ++is) {
        const int ci = is * 256 + tid;
        const int row = ci & 15, kg = (ci >> 4) & 3, mf = ci >> 6;
        gload16(Wp + (size_t)(mf * 16 + row) * CC + c0 + kg * 8,
                Alc + is * 4096 + wave * 1024);
      }
#pragma unroll
      for (int it = 0; it < 2; ++it) {
        const int vi = it * 256 + tid;
        const int col = vi & 15, kg = (vi >> 4) & 3, nf = vi >> 6;
        const int w = nf * 16 + col;
        short tmp[8];
#pragma unroll
        for (int e = 0; e < 8; ++e) {
          const int r = (kc * 4 + kg) * 8 + e;
          tmp[e] = *(const short*)(Brc + r * 256 + (((w >> 3) ^ (r & 15)) << 4) + (w & 7) * 2);
        }
        *(s16x8*)(Bfc + ((nf * 64 + kg * 16 + col) << 4)) = *(const s16x8*)tmp;
      }
      vmdrain();
      __syncthreads();
      s16x8 a[6], bf[4];
#pragma unroll
      for (int mi = 0; mi < 6; ++mi)
        a[mi] = *(const s16x8*)(Alc + ((wm * 6 + mi) << 10) + (lane << 4));
#pragma unroll
      for (int j = 0; j < 4; ++j)
        bf[j] = *(const s16x8*)(Bfc + (((wn * 4 + j) * 64 + lane) << 4));
#pragma unroll
      for (int mi = 0; mi < 6; ++mi)
#pragma unroll
        for (int j = 0; j < 4; ++j)
          acc[mi][j] = __builtin_amdgcn_mfma_f32_16x16x32_bf16(a[mi], bf[j], acc[mi][j], 0, 0, 0);
      __syncthreads();
    }
  }
  const int r0 = (lane >> 4) * 4, cl = lane & 15;
#pragma unroll
  for (int mi = 0; mi < 6; ++mi) {
    const int o = (wm * 6 + mi) * 16 + r0;
#pragma unroll
    for (int j = 0; j < 4; ++j) {
      const int w = (wn * 4 + j) * 16 + cl;
      float* dst = out + ((size_t)b * CC + o) * HW + i * 128 + w;
#pragma unroll
      for (int r = 0; r < 4; ++r) dst[(size_t)r * HW] = acc[mi][j][r];
    }
  }
}

extern "C" void kernel_launch(void* const* d_in, const int* in_sizes, int n_in,
                              void* d_out, int out_size, void* d_ws, size_t ws_size,
                              hipStream_t stream) {
  const float* x     = (const float*)d_in[0];
  const float* wqkv  = (const float*)d_in[1];
  const float* wdw   = (const float*)d_in[2];
  const float* wproj = (const float*)d_in[3];
  const float* temp  = (const float*)d_in[4];

  char* ws = (char*)d_ws;
  __hip_bfloat16* xTb    = (__hip_bfloat16*)(ws + OFF_XT);
  __hip_bfloat16* vt     = (__hip_bfloat16*)(ws + OFF_XT);   // xT dead after k_gemm
  __hip_bfloat16* Wq     = (__hip_bfloat16*)(ws + OFF_WQ);
  __hip_bfloat16* Wp     = (__hip_bfloat16*)(ws + OFF_WP);
  __hip_bfloat16* qkvraw = (__hip_bfloat16*)(ws + OFF_RAW);
  __hip_bfloat16* pvout  = (__hip_bfloat16*)(ws + OFF_RAW);  // qkvraw dead after dwconv
  __hip_bfloat16* qkvdw  = (__hip_bfloat16*)(ws + OFF_DW);
  float* sp    = (float*)(ws + OFF_SP);
  float* psum  = (float*)(ws + OFF_PS);                      // after 4 used S chunks
  __hip_bfloat16* atb = (__hip_bfloat16*)(ws + OFF_ATB);
  float* rq    = (float*)(ws + OFF_RQ);
  float* rk    = (float*)(ws + OFF_RK);

  k_cvt_w2<<<dim3((C3 * CC + CC * CC + 255) / 256), 256, 0, stream>>>(wqkv, C3 * CC, wproj, CC * CC, Wq);
  k_cvt_t<<<dim3(HW / 64, CC / 32, BB), 256, 0, stream>>>(x, xTb);
  k_gemm<<<dim3(HW / 512, C3 / 96, BB), 256, 0, stream>>>(xTb, Wq, qkvraw);
  k_dwconv<<<dim3(HH / 32, C3, BB), 256, 0, stream>>>(qkvraw, wdw, qkvdw, vt, psum);
  k_norms2<<<dim3(HH, NH, 2 * BB), 64, 0, stream>>>(psum, rq, rk);
  k_qkm<<<dim3(4, 32, 2), 256, 0, stream>>>(qkvdw, sp);
  k_softmax<<<dim3(HH / 4, 32), 256, 0, stream>>>(sp, rq, rk, temp, atb);
  k_pvm<<<dim3(24, 32), 256, 0, stream>>>(atb, vt, pvout);
  k_proj<<<dim3(HH, BB), 256, 0, stream>>>(pvout, Wp, (float*)d_out);
}